// Round 3
// baseline (2575.179 us; speedup 1.0000x reference)
//
#include <hip/hip_runtime.h>
#include <hip/hip_bf16.h>
#include <math.h>

typedef __bf16 bf16_t;
typedef __bf16 bf16x8 __attribute__((ext_vector_type(8)));
typedef __bf16 bf16x4 __attribute__((ext_vector_type(4)));
typedef float  f32x4  __attribute__((ext_vector_type(4)));

#define DEVI static __device__ __forceinline__

DEVI f32x4 mfma16(bf16x8 a, bf16x8 b, f32x4 c) {
    return __builtin_amdgcn_mfma_f32_16x16x32_bf16(a, b, c, 0, 0, 0);
}

// ---------------- fp32 -> bf16 cast (4 elems/thread) ----------------
__global__ void cast4_k(const float* __restrict__ src, bf16_t* __restrict__ dst, int n4) {
    int i = blockIdx.x * 256 + threadIdx.x;
    if (i < n4) {
        float4 v = ((const float4*)src)[i];
        bf16x4 o;
        o[0] = (bf16_t)v.x; o[1] = (bf16_t)v.y; o[2] = (bf16_t)v.z; o[3] = (bf16_t)v.w;
        *(bf16x4*)(dst + (long)i * 4) = o;
    }
}

// ---------------- LayerNorm: fp32 in -> bf16 out, one wave per row (E=256) ----------------
__global__ __launch_bounds__(256) void ln_k(const float* __restrict__ x,
                                            const float* __restrict__ g,
                                            const float* __restrict__ bta,
                                            bf16_t* __restrict__ out) {
    int wave = threadIdx.x >> 6, lane = threadIdx.x & 63;
    int row = blockIdx.x * 4 + wave;
    const float4 v = *(const float4*)(x + (long)row * 256 + lane * 4);
    float s  = v.x + v.y + v.z + v.w;
    float s2 = v.x * v.x + v.y * v.y + v.z * v.z + v.w * v.w;
    for (int m = 1; m < 64; m <<= 1) { s += __shfl_xor(s, m); s2 += __shfl_xor(s2, m); }
    float mu  = s * (1.f / 256.f);
    float var = s2 * (1.f / 256.f) - mu * mu;
    float rs  = rsqrtf(var + 1e-5f);
    float4 gg = *(const float4*)(g + lane * 4);
    float4 bb = *(const float4*)(bta + lane * 4);
    bf16x4 o;
    o[0] = (bf16_t)((v.x - mu) * rs * gg.x + bb.x);
    o[1] = (bf16_t)((v.y - mu) * rs * gg.y + bb.y);
    o[2] = (bf16_t)((v.z - mu) * rs * gg.z + bb.z);
    o[3] = (bf16_t)((v.w - mu) * rs * gg.w + bb.w);
    *(bf16x4*)(out + (long)row * 256 + lane * 4) = o;
}

// ---------------- generic bf16 MFMA GEMM: C[M,N] = A[M,K] @ W[N,K]^T + bias ----------------
enum { EPI_PROJ = 0, EPI_QKV = 1, EPI_RESID = 2, EPI_GELU = 3, EPI_XPROJ = 4 };

template <int EPI>
__global__ __launch_bounds__(256) void gemm_bt(
    const bf16_t* __restrict__ A, int lda,
    const bf16_t* __restrict__ W, int ldw,
    const float* __restrict__ bias,
    int N, int K,
    bf16_t* __restrict__ outb, int ldob,
    float* __restrict__ outf,
    const float* __restrict__ pos,
    bf16_t* __restrict__ vt) {
    int tiles_n = N >> 6;
    int tm = blockIdx.x / tiles_n, tn = blockIdx.x % tiles_n;
    int wave = threadIdx.x >> 6, lane = threadIdx.x & 63;
    int quad = lane >> 4, l16 = lane & 15;
    int m0 = tm * 64 + wave * 16;
    int n0 = tn * 64;
    const bf16_t* a_ptr = A + (long)(m0 + l16) * lda + quad * 8;
    const bf16_t* w_ptr = W + (long)(n0 + l16) * ldw + quad * 8;
    f32x4 zero = {0.f, 0.f, 0.f, 0.f};
    f32x4 acc[4] = {zero, zero, zero, zero};
    for (int k = 0; k < K; k += 32) {
        bf16x8 af = *(const bf16x8*)(a_ptr + k);
#pragma unroll
        for (int c = 0; c < 4; ++c) {
            bf16x8 wf = *(const bf16x8*)(w_ptr + (long)c * 16 * ldw + k);
            acc[c] = mfma16(af, wf, acc[c]);
        }
    }
#pragma unroll
    for (int c = 0; c < 4; ++c) {
        int col = n0 + c * 16 + l16;
        float bv = bias[col];
#pragma unroll
        for (int r = 0; r < 4; ++r) {
            int row = m0 + quad * 4 + r;
            float v = acc[c][r] + bv;
            if (EPI == EPI_PROJ) {
                int s = row & 1023;
                v += pos[(long)s * 256 + col];
                outf[(long)row * 256 + col] = v;
            } else if (EPI == EPI_QKV) {
                outb[(long)row * ldob + col] = (bf16_t)v;
                if (col >= 512) {  // emit V transposed: Vt[b*8+h][d][s]
                    int b = row >> 10, s = row & 1023;
                    int hh = (col - 512) >> 5, d = (col - 512) & 31;
                    vt[(((long)(b * 8 + hh) * 32 + d) << 10) + s] = (bf16_t)v;
                }
            } else if (EPI == EPI_RESID) {
                float* p = outf + (long)row * 256 + col;
                *p = *p + v;
            } else if (EPI == EPI_GELU) {
                float gg = 0.5f * v * (1.f + erff(v * 0.70710678118654752f));
                outb[(long)row * ldob + col] = (bf16_t)gg;
            } else if (EPI == EPI_XPROJ) {
                // xp fp32, layout [s][b][e] (row-major over (s*16+b))
                int b = row >> 10, s = row & 1023;
                outf[((long)(s * 16 + b)) * 256 + col] = v;
            }
        }
    }
}

// ---------------- flash attention: one wave = 16 q rows, online softmax ----------------
__global__ __launch_bounds__(256) void attn_k(const bf16_t* __restrict__ qkv,  // [16384,768]
                                              const bf16_t* __restrict__ vt,   // [128][32][1024]
                                              bf16_t* __restrict__ ctx) {      // [16384,256]
    __shared__ bf16_t Pbuf[4][16 * 32];
    int wave = threadIdx.x >> 6, lane = threadIdx.x & 63;
    int quad = lane >> 4, l16 = lane & 15;
    int bh = blockIdx.x >> 4;
    int b = bh >> 3, h = bh & 7;
    int q0 = ((blockIdx.x & 15) * 4 + wave) * 16;
    const bf16_t* qbase = qkv + (long)(b * 1024 + q0 + l16) * 768 + h * 32 + quad * 8;
    bf16x8 qf = *(const bf16x8*)qbase;  // DH=32 == MFMA K: load Q fragment once
    const bf16_t* kbase = qkv + (long)(b * 1024 + l16) * 768 + 256 + h * 32 + quad * 8;
    const bf16_t* vbase = vt + ((long)bh * 32) * 1024;
    f32x4 zero = {0.f, 0.f, 0.f, 0.f};
    f32x4 ca = zero, cb = zero;
    float mrow[4] = {-INFINITY, -INFINITY, -INFINITY, -INFINITY};
    float lrow[4] = {0.f, 0.f, 0.f, 0.f};
    bf16_t* P = Pbuf[wave];
    const float sc = 0.17677669529663687f;  // 1/sqrt(32)
    for (int kb = 0; kb < 1024; kb += 32) {
        bf16x8 kf0 = *(const bf16x8*)(kbase + (long)kb * 768);
        bf16x8 kf1 = *(const bf16x8*)(kbase + (long)(kb + 16) * 768);
        f32x4 s0 = mfma16(qf, kf0, zero);
        f32x4 s1 = mfma16(qf, kf1, zero);
        float p0[4], p1[4];
#pragma unroll
        for (int r = 0; r < 4; ++r) {
            float a0 = s0[r] * sc, a1 = s1[r] * sc;
            float mx = fmaxf(a0, a1);
            mx = fmaxf(mx, __shfl_xor(mx, 1));
            mx = fmaxf(mx, __shfl_xor(mx, 2));
            mx = fmaxf(mx, __shfl_xor(mx, 4));
            mx = fmaxf(mx, __shfl_xor(mx, 8));
            float mn = fmaxf(mrow[r], mx);
            float alpha = __expf(mrow[r] - mn);
            mrow[r] = mn;
            float e0 = __expf(a0 - mn), e1 = __expf(a1 - mn);
            float rs = e0 + e1;
            rs += __shfl_xor(rs, 1);
            rs += __shfl_xor(rs, 2);
            rs += __shfl_xor(rs, 4);
            rs += __shfl_xor(rs, 8);
            lrow[r] = lrow[r] * alpha + rs;
            ca[r] *= alpha;
            cb[r] *= alpha;
            p0[r] = e0; p1[r] = e1;
        }
#pragma unroll
        for (int r = 0; r < 4; ++r) {
            P[(quad * 4 + r) * 32 + l16] = (bf16_t)p0[r];
            P[(quad * 4 + r) * 32 + 16 + l16] = (bf16_t)p1[r];
        }
        __syncthreads();
        bf16x8 pf = *(const bf16x8*)(P + l16 * 32 + quad * 8);  // A-layout read-back
        bf16x8 vf0 = *(const bf16x8*)(vbase + (long)l16 * 1024 + kb + quad * 8);
        bf16x8 vf1 = *(const bf16x8*)(vbase + (long)(16 + l16) * 1024 + kb + quad * 8);
        ca = mfma16(pf, vf0, ca);
        cb = mfma16(pf, vf1, cb);
        __syncthreads();
    }
#pragma unroll
    for (int r = 0; r < 4; ++r) {
        float inv = 1.f / lrow[r];
        long row = (long)(b * 1024 + q0 + quad * 4 + r);
        ctx[row * 256 + h * 32 + l16] = (bf16_t)(ca[r] * inv);
        ctx[row * 256 + h * 32 + 16 + l16] = (bf16_t)(cb[r] * inv);
    }
}

// ---------------- RNN scan v3: operand-swapped MFMA, 4 waves (1/SIMD) ----------------
// D[m=out_col][n=batch]: A = Wh fragments (register/AGPR resident), B = h from LDS
// (read pattern identical to v2). C-layout gives each thread 4 CONSECUTIVE out cols
// for batch=l16 -> ds_write_b64 writeback (was 16x ds_write_b16), packed cvts.
// x stays fp32 and initializes accL (no adds, no x quantization). relu(tanh(u)) == mask.
__global__ __launch_bounds__(256, 1) void scan_k(const float* __restrict__ xp,    // [1024][16][256] fp32
                                                 const bf16_t* __restrict__ wi2h, // [256][512]
                                                 const bf16_t* __restrict__ wh2o, // [256][256]
                                                 const float* __restrict__ h2o_b,
                                                 const float* __restrict__ cls_W,
                                                 const float* __restrict__ cls_b,
                                                 const float* __restrict__ h0,
                                                 float* __restrict__ d_out) {
    constexpr int HS = 264;  // padded LDS row stride (bf16 elems)
    __shared__ bf16_t hbuf[2][16 * HS];
    __shared__ float ssm_lds[16 * 256];
    int tid = threadIdx.x;
    int w = tid >> 6, lane = tid & 63, quad = lane >> 4, l16 = lane & 15;
    // A-fragments of Wh for this wave's 64 out cols: A[m=l16][k=quad*8+j], m = w*64+c*16+l16
    bf16x8 whf[4][8];
#pragma unroll
    for (int c = 0; c < 4; ++c) {
        const bf16_t* p = wi2h + (long)(w * 64 + c * 16 + l16) * 512 + 256 + quad * 8;
#pragma unroll
        for (int ks = 0; ks < 8; ++ks) whf[c][ks] = *(const bf16x8*)(p + ks * 32);
    }
    // h0 -> hbuf[0] (bf16, [batch][col] padded rows)
    {
        int b = tid >> 4, e0 = (tid & 15) * 16;
        const float4* src = (const float4*)(h0 + b * 256 + e0);
        bf16_t* dst = &hbuf[0][b * HS + e0];
#pragma unroll
        for (int j = 0; j < 4; ++j) {
            float4 v = src[j];
            bf16x4 o;
            o[0] = (bf16_t)v.x; o[1] = (bf16_t)v.y; o[2] = (bf16_t)v.z; o[3] = (bf16_t)v.w;
            *(bf16x4*)(dst + j * 4) = o;
        }
    }
    __syncthreads();
    f32x4 zero = {0.f, 0.f, 0.f, 0.f};
    // x for (batch=l16, cols w*64+c*16+quad*4 .. +3): one f32x4 per c, prefetched 1 step
    const long xoff = (long)l16 * 256 + w * 64 + quad * 4;
    f32x4 xcur[4], xnxt[4];
#pragma unroll
    for (int c = 0; c < 4; ++c) xcur[c] = *(const f32x4*)(xp + xoff + c * 16);
    for (int t = 0; t < 1024; ++t) {
        int tn = (t + 1) & 1023;  // wraps to valid addr; value unused at t=1023
        const float* xb_n = xp + (long)tn * 4096 + xoff;
#pragma unroll
        for (int c = 0; c < 4; ++c) xnxt[c] = *(const f32x4*)(xb_n + c * 16);
        const bf16_t* hb = hbuf[t & 1];
        f32x4 accL[4], accH[4];
#pragma unroll
        for (int c = 0; c < 4; ++c) { accL[c] = xcur[c]; accH[c] = zero; }
        bf16x8 hfrag[4];
#pragma unroll
        for (int ks = 0; ks < 4; ++ks)
            hfrag[ks] = *(const bf16x8*)(hb + l16 * HS + ks * 32 + quad * 8);
#pragma unroll
        for (int ks = 0; ks < 4; ++ks)
#pragma unroll
            for (int c = 0; c < 4; ++c) accL[c] = mfma16(whf[c][ks], hfrag[ks], accL[c]);
#pragma unroll
        for (int ks = 0; ks < 4; ++ks)
            hfrag[ks] = *(const bf16x8*)(hb + l16 * HS + (ks + 4) * 32 + quad * 8);
#pragma unroll
        for (int ks = 0; ks < 4; ++ks)
#pragma unroll
            for (int c = 0; c < 4; ++c) accH[c] = mfma16(whf[c][ks + 4], hfrag[ks], accH[c]);
        bf16_t* hn = hbuf[(t + 1) & 1];
#pragma unroll
        for (int c = 0; c < 4; ++c) {
            f32x4 u4 = accL[c] + accH[c];
            bf16x4 o;
#pragma unroll
            for (int r = 0; r < 4; ++r) {
                float ex = fminf(__expf(-2.f * u4[r]), 1e37f);
                float th = (1.f - ex) * __builtin_amdgcn_rcpf(1.f + ex);
                o[r] = (bf16_t)fmaxf(th, 0.f);  // relu(tanh(u)) == tanh(u)*(u>0)
            }
            *(bf16x4*)(hn + l16 * HS + w * 64 + c * 16 + quad * 4) = o;
            xcur[c] = xnxt[c];
        }
        __syncthreads();
    }
    // ssm = h_final @ h2o^T + b (same swapped structure; h_final in hbuf[0])
    const bf16_t* hf = hbuf[0];
    float* ssm_out = d_out + 32 + 4194304;
#pragma unroll
    for (int c = 0; c < 4; ++c) {
        const bf16_t* p = wh2o + (long)(w * 64 + c * 16 + l16) * 256 + quad * 8;
        f32x4 a = zero;
#pragma unroll
        for (int ks = 0; ks < 8; ++ks) {
            bf16x8 af = *(const bf16x8*)(hf + l16 * HS + ks * 32 + quad * 8);
            a = mfma16(*(const bf16x8*)(p + ks * 32), af, a);
        }
        float4 bv = *(const float4*)(h2o_b + w * 64 + c * 16 + quad * 4);
        float4 v = {a[0] + bv.x, a[1] + bv.y, a[2] + bv.z, a[3] + bv.w};
        *(float4*)(ssm_out + (long)l16 * 256 + w * 64 + c * 16 + quad * 4) = v;
        *(float4*)(&ssm_lds[l16 * 256 + w * 64 + c * 16 + quad * 4]) = v;
    }
    __syncthreads();
    // logits + sigmoid: 16 threads/batch, shfl-reduce
    {
        int b = tid >> 4, sub = tid & 15;
        float s = 0.f;
#pragma unroll
        for (int j = 0; j < 16; ++j) s += ssm_lds[b * 256 + sub * 16 + j] * cls_W[sub * 16 + j];
        s += __shfl_xor(s, 1);
        s += __shfl_xor(s, 2);
        s += __shfl_xor(s, 4);
        s += __shfl_xor(s, 8);
        if (sub == 0) {
            float lg = s + cls_b[0];
            d_out[b] = lg;
            d_out[16 + b] = 1.f / (1.f + __expf(-lg));
        }
    }
}

extern "C" void kernel_launch(void* const* d_in, const int* in_sizes, int n_in,
                              void* d_out, int out_size, void* d_ws, size_t ws_size,
                              hipStream_t stream) {
    const float* text_emb = (const float*)d_in[0];
    const float* pos_emb  = (const float*)d_in[4];
    const float* text_W   = (const float*)d_in[5];
    const float* text_b   = (const float*)d_in[6];
    const float* ln1_g    = (const float*)d_in[9];
    const float* ln1_b    = (const float*)d_in[10];
    const float* qkv_W    = (const float*)d_in[11];
    const float* qkv_b    = (const float*)d_in[12];
    const float* out_W    = (const float*)d_in[13];
    const float* out_b    = (const float*)d_in[14];
    const float* ln2_g    = (const float*)d_in[15];
    const float* ln2_b    = (const float*)d_in[16];
    const float* ffn_W1   = (const float*)d_in[17];
    const float* ffn_b1   = (const float*)d_in[18];
    const float* ffn_W2   = (const float*)d_in[19];
    const float* ffn_b2   = (const float*)d_in[20];
    const float* cls_W    = (const float*)d_in[21];
    const float* cls_b    = (const float*)d_in[22];
    const float* i2h_W    = (const float*)d_in[23];
    const float* i2h_b    = (const float*)d_in[24];
    const float* h2o_W    = (const float*)d_in[25];
    const float* h2o_b    = (const float*)d_in[26];
    const float* h0       = (const float*)d_in[27];

    char* ws = (char*)d_ws;
    bf16_t* wtext = (bf16_t*)(ws + 0);         // 196608 elems
    bf16_t* wqkv  = (bf16_t*)(ws + 393216);    // 2x196608
    bf16_t* wout  = (bf16_t*)(ws + 1179648);   // 2x65536
    bf16_t* wff1  = (bf16_t*)(ws + 1441792);   // 2x262144
    bf16_t* wff2  = (bf16_t*)(ws + 2490368);   // 2x262144
    bf16_t* wi2h  = (bf16_t*)(ws + 3538944);   // 131072
    bf16_t* wh2o  = (bf16_t*)(ws + 3801088);   // 65536
    bf16_t* buf1  = (bf16_t*)(ws + 4194304);   // 33.5 MB: text_bf16 / ffn_hidden
    bf16_t* buf2  = (bf16_t*)(ws + 37748736);  // 25.2 MB: qkv bf16 (later xp fp32)
    bf16_t* buf3  = (bf16_t*)(ws + 62914560);  // 8.4 MB: ln_out / x_bf16
    bf16_t* buf4  = (bf16_t*)(ws + 71303168);  // 8.4 MB: ctx bf16
    bf16_t* buf5  = (bf16_t*)(ws + 79691776);  // 8.4 MB: Vt bf16
    float*  xp    = (float*)(ws + 37748736);   // alias buf2 (qkv dead by then): fp32 [1024][16][256]
    float*  xbuf  = (float*)d_out + 32;        // residual stream lives in final_vector slot

    auto cast = [&](const float* s, bf16_t* d, long n) {
        cast4_k<<<(int)((n / 4 + 255) / 256), 256, 0, stream>>>(s, d, (int)(n / 4));
    };
    cast(text_W, wtext, 196608);
    cast(qkv_W, wqkv, 393216);
    cast(out_W, wout, 131072);
    cast(ffn_W1, wff1, 524288);
    cast(ffn_W2, wff2, 524288);
    cast(i2h_W, wi2h, 131072);
    cast(h2o_W, wh2o, 65536);
    cast(text_emb, buf1, (long)16384 * 768);

    // x = text_bf16 @ text_W^T + b + pos
    gemm_bt<EPI_PROJ><<<256 * 4, 256, 0, stream>>>(buf1, 768, wtext, 768, text_b, 256, 768,
                                                   nullptr, 0, xbuf, pos_emb, nullptr);
    for (int l = 0; l < 2; ++l) {
        ln_k<<<4096, 256, 0, stream>>>(xbuf, ln1_g + l * 256, ln1_b + l * 256, buf3);
        gemm_bt<EPI_QKV><<<256 * 12, 256, 0, stream>>>(buf3, 256, wqkv + l * 196608, 256,
                                                       qkv_b + l * 768, 768, 256,
                                                       buf2, 768, nullptr, nullptr, buf5);
        attn_k<<<2048, 256, 0, stream>>>(buf2, buf5, buf4);
        gemm_bt<EPI_RESID><<<256 * 4, 256, 0, stream>>>(buf4, 256, wout + l * 65536, 256,
                                                        out_b + l * 256, 256, 256,
                                                        nullptr, 0, xbuf, nullptr, nullptr);
        ln_k<<<4096, 256, 0, stream>>>(xbuf, ln2_g + l * 256, ln2_b + l * 256, buf3);
        gemm_bt<EPI_GELU><<<256 * 16, 256, 0, stream>>>(buf3, 256, wff1 + l * 262144, 256,
                                                        ffn_b1 + l * 1024, 1024, 256,
                                                        buf1, 1024, nullptr, nullptr, nullptr);
        gemm_bt<EPI_RESID><<<256 * 4, 256, 0, stream>>>(buf1, 1024, wff2 + l * 262144, 1024,
                                                        ffn_b2 + l * 256, 256, 1024,
                                                        nullptr, 0, xbuf, nullptr, nullptr);
    }
    // RNN head
    cast(xbuf, buf3, (long)16384 * 256);
    gemm_bt<EPI_XPROJ><<<256 * 4, 256, 0, stream>>>(buf3, 256, wi2h, 512, i2h_b, 256, 256,
                                                    nullptr, 0, xp, nullptr, nullptr);
    scan_k<<<1, 256, 0, stream>>>(xp, wi2h, wh2o, h2o_b, cls_W, cls_b, h0, (float*)d_out);
}

// Round 4
// 2055.904 us; speedup vs baseline: 1.2526x; 1.2526x over previous
//
#include <hip/hip_runtime.h>
#include <hip/hip_bf16.h>
#include <math.h>

typedef __bf16 bf16_t;
typedef __bf16 bf16x8 __attribute__((ext_vector_type(8)));
typedef __bf16 bf16x4 __attribute__((ext_vector_type(4)));
typedef float  f32x4  __attribute__((ext_vector_type(4)));

#define DEVI static __device__ __forceinline__

// workgroup barrier WITHOUT the vmcnt(0) drain __syncthreads() emits:
// LDS ordering only (lgkmcnt). Global prefetch loads stay in flight across it;
// the compiler still inserts vmcnt(N) at the register USE of loaded values.
#define BARRIER_LGKM() __asm volatile("s_waitcnt lgkmcnt(0)\n\ts_barrier" ::: "memory")

DEVI f32x4 mfma16(bf16x8 a, bf16x8 b, f32x4 c) {
    return __builtin_amdgcn_mfma_f32_16x16x32_bf16(a, b, c, 0, 0, 0);
}

// ---------------- fp32 -> bf16 cast (4 elems/thread) ----------------
__global__ void cast4_k(const float* __restrict__ src, bf16_t* __restrict__ dst, int n4) {
    int i = blockIdx.x * 256 + threadIdx.x;
    if (i < n4) {
        float4 v = ((const float4*)src)[i];
        bf16x4 o;
        o[0] = (bf16_t)v.x; o[1] = (bf16_t)v.y; o[2] = (bf16_t)v.z; o[3] = (bf16_t)v.w;
        *(bf16x4*)(dst + (long)i * 4) = o;
    }
}

// ---------------- LayerNorm: fp32 in -> bf16 out, one wave per row (E=256) ----------------
__global__ __launch_bounds__(256) void ln_k(const float* __restrict__ x,
                                            const float* __restrict__ g,
                                            const float* __restrict__ bta,
                                            bf16_t* __restrict__ out) {
    int wave = threadIdx.x >> 6, lane = threadIdx.x & 63;
    int row = blockIdx.x * 4 + wave;
    const float4 v = *(const float4*)(x + (long)row * 256 + lane * 4);
    float s  = v.x + v.y + v.z + v.w;
    float s2 = v.x * v.x + v.y * v.y + v.z * v.z + v.w * v.w;
    for (int m = 1; m < 64; m <<= 1) { s += __shfl_xor(s, m); s2 += __shfl_xor(s2, m); }
    float mu  = s * (1.f / 256.f);
    float var = s2 * (1.f / 256.f) - mu * mu;
    float rs  = rsqrtf(var + 1e-5f);
    float4 gg = *(const float4*)(g + lane * 4);
    float4 bb = *(const float4*)(bta + lane * 4);
    bf16x4 o;
    o[0] = (bf16_t)((v.x - mu) * rs * gg.x + bb.x);
    o[1] = (bf16_t)((v.y - mu) * rs * gg.y + bb.y);
    o[2] = (bf16_t)((v.z - mu) * rs * gg.z + bb.z);
    o[3] = (bf16_t)((v.w - mu) * rs * gg.w + bb.w);
    *(bf16x4*)(out + (long)row * 256 + lane * 4) = o;
}

// ---------------- generic bf16 MFMA GEMM: C[M,N] = A[M,K] @ W[N,K]^T + bias ----------------
enum { EPI_PROJ = 0, EPI_QKV = 1, EPI_RESID = 2, EPI_GELU = 3, EPI_XPROJ = 4 };

template <int EPI>
__global__ __launch_bounds__(256) void gemm_bt(
    const bf16_t* __restrict__ A, int lda,
    const bf16_t* __restrict__ W, int ldw,
    const float* __restrict__ bias,
    int N, int K,
    bf16_t* __restrict__ outb, int ldob,
    float* __restrict__ outf,
    const float* __restrict__ pos,
    bf16_t* __restrict__ vt) {
    int tiles_n = N >> 6;
    int tm = blockIdx.x / tiles_n, tn = blockIdx.x % tiles_n;
    int wave = threadIdx.x >> 6, lane = threadIdx.x & 63;
    int quad = lane >> 4, l16 = lane & 15;
    int m0 = tm * 64 + wave * 16;
    int n0 = tn * 64;
    const bf16_t* a_ptr = A + (long)(m0 + l16) * lda + quad * 8;
    const bf16_t* w_ptr = W + (long)(n0 + l16) * ldw + quad * 8;
    f32x4 zero = {0.f, 0.f, 0.f, 0.f};
    f32x4 acc[4] = {zero, zero, zero, zero};
    for (int k = 0; k < K; k += 32) {
        bf16x8 af = *(const bf16x8*)(a_ptr + k);
#pragma unroll
        for (int c = 0; c < 4; ++c) {
            bf16x8 wf = *(const bf16x8*)(w_ptr + (long)c * 16 * ldw + k);
            acc[c] = mfma16(af, wf, acc[c]);
        }
    }
#pragma unroll
    for (int c = 0; c < 4; ++c) {
        int col = n0 + c * 16 + l16;
        float bv = bias[col];
#pragma unroll
        for (int r = 0; r < 4; ++r) {
            int row = m0 + quad * 4 + r;
            float v = acc[c][r] + bv;
            if (EPI == EPI_PROJ) {
                int s = row & 1023;
                v += pos[(long)s * 256 + col];
                outf[(long)row * 256 + col] = v;
            } else if (EPI == EPI_QKV) {
                outb[(long)row * ldob + col] = (bf16_t)v;
                if (col >= 512) {  // emit V transposed: Vt[b*8+h][d][s]
                    int b = row >> 10, s = row & 1023;
                    int hh = (col - 512) >> 5, d = (col - 512) & 31;
                    vt[(((long)(b * 8 + hh) * 32 + d) << 10) + s] = (bf16_t)v;
                }
            } else if (EPI == EPI_RESID) {
                float* p = outf + (long)row * 256 + col;
                *p = *p + v;
            } else if (EPI == EPI_GELU) {
                float gg = 0.5f * v * (1.f + erff(v * 0.70710678118654752f));
                outb[(long)row * ldob + col] = (bf16_t)gg;
            } else if (EPI == EPI_XPROJ) {
                // xp bf16, thread-interleaved [s][consumer_tid][16]: consumer thread
                // tid=w*64+quad*16+l16 holds (batch=l16, col=w*64+c*16+quad*4+r) at c*4+r
                int b = row >> 10, s = row & 1023;
                int tcons = ((col >> 6) << 6) + (((col >> 2) & 3) << 4) + b;
                outb[((long)s * 256 + tcons) * 16 + ((col >> 4) & 3) * 4 + (col & 3)] = (bf16_t)v;
            }
        }
    }
}

// ---------------- flash attention: one wave = 16 q rows, online softmax ----------------
__global__ __launch_bounds__(256) void attn_k(const bf16_t* __restrict__ qkv,  // [16384,768]
                                              const bf16_t* __restrict__ vt,   // [128][32][1024]
                                              bf16_t* __restrict__ ctx) {      // [16384,256]
    __shared__ bf16_t Pbuf[4][16 * 32];
    int wave = threadIdx.x >> 6, lane = threadIdx.x & 63;
    int quad = lane >> 4, l16 = lane & 15;
    int bh = blockIdx.x >> 4;
    int b = bh >> 3, h = bh & 7;
    int q0 = ((blockIdx.x & 15) * 4 + wave) * 16;
    const bf16_t* qbase = qkv + (long)(b * 1024 + q0 + l16) * 768 + h * 32 + quad * 8;
    bf16x8 qf = *(const bf16x8*)qbase;  // DH=32 == MFMA K: load Q fragment once
    const bf16_t* kbase = qkv + (long)(b * 1024 + l16) * 768 + 256 + h * 32 + quad * 8;
    const bf16_t* vbase = vt + ((long)bh * 32) * 1024;
    f32x4 zero = {0.f, 0.f, 0.f, 0.f};
    f32x4 ca = zero, cb = zero;
    float mrow[4] = {-INFINITY, -INFINITY, -INFINITY, -INFINITY};
    float lrow[4] = {0.f, 0.f, 0.f, 0.f};
    bf16_t* P = Pbuf[wave];
    const float sc = 0.17677669529663687f;  // 1/sqrt(32)
    for (int kb = 0; kb < 1024; kb += 32) {
        bf16x8 kf0 = *(const bf16x8*)(kbase + (long)kb * 768);
        bf16x8 kf1 = *(const bf16x8*)(kbase + (long)(kb + 16) * 768);
        f32x4 s0 = mfma16(qf, kf0, zero);
        f32x4 s1 = mfma16(qf, kf1, zero);
        float p0[4], p1[4];
#pragma unroll
        for (int r = 0; r < 4; ++r) {
            float a0 = s0[r] * sc, a1 = s1[r] * sc;
            float mx = fmaxf(a0, a1);
            mx = fmaxf(mx, __shfl_xor(mx, 1));
            mx = fmaxf(mx, __shfl_xor(mx, 2));
            mx = fmaxf(mx, __shfl_xor(mx, 4));
            mx = fmaxf(mx, __shfl_xor(mx, 8));
            float mn = fmaxf(mrow[r], mx);
            float alpha = __expf(mrow[r] - mn);
            mrow[r] = mn;
            float e0 = __expf(a0 - mn), e1 = __expf(a1 - mn);
            float rs = e0 + e1;
            rs += __shfl_xor(rs, 1);
            rs += __shfl_xor(rs, 2);
            rs += __shfl_xor(rs, 4);
            rs += __shfl_xor(rs, 8);
            lrow[r] = lrow[r] * alpha + rs;
            ca[r] *= alpha;
            cb[r] *= alpha;
            p0[r] = e0; p1[r] = e1;
        }
#pragma unroll
        for (int r = 0; r < 4; ++r) {
            P[(quad * 4 + r) * 32 + l16] = (bf16_t)p0[r];
            P[(quad * 4 + r) * 32 + 16 + l16] = (bf16_t)p1[r];
        }
        BARRIER_LGKM();
        bf16x8 pf = *(const bf16x8*)(P + l16 * 32 + quad * 8);  // A-layout read-back
        bf16x8 vf0 = *(const bf16x8*)(vbase + (long)l16 * 1024 + kb + quad * 8);
        bf16x8 vf1 = *(const bf16x8*)(vbase + (long)(16 + l16) * 1024 + kb + quad * 8);
        ca = mfma16(pf, vf0, ca);
        cb = mfma16(pf, vf1, cb);
        BARRIER_LGKM();
    }
#pragma unroll
    for (int r = 0; r < 4; ++r) {
        float inv = 1.f / lrow[r];
        long row = (long)(b * 1024 + q0 + quad * 4 + r);
        ctx[row * 256 + h * 32 + l16] = (bf16_t)(ca[r] * inv);
        ctx[row * 256 + h * 32 + 16 + l16] = (bf16_t)(cb[r] * inv);
    }
}

// ---------------- RNN scan v4: lgkm-only barrier + 4-deep coalesced bf16 x-ring ----------------
// Swapped MFMA: D[m=out_col][n=batch], A = Wh register fragments, B = h from LDS.
// x stream: bf16 [t][tid][16] -> two 16B coalesced loads/thread/step, issued at t,
// consumed at t+4; loads stay in flight across the lgkm-only barrier (no vmcnt drain).
__global__ __launch_bounds__(256, 1) void scan_k(const bf16_t* __restrict__ xpb,  // [1024][256][16]
                                                 const bf16_t* __restrict__ wi2h, // [256][512]
                                                 const bf16_t* __restrict__ wh2o, // [256][256]
                                                 const float* __restrict__ h2o_b,
                                                 const float* __restrict__ cls_W,
                                                 const float* __restrict__ cls_b,
                                                 const float* __restrict__ h0,
                                                 float* __restrict__ d_out) {
    constexpr int HS = 264;  // padded LDS row stride (bf16 elems)
    __shared__ bf16_t hbuf[2][16 * HS];
    __shared__ float ssm_lds[16 * 256];
    int tid = threadIdx.x;
    int w = tid >> 6, lane = tid & 63, quad = lane >> 4, l16 = lane & 15;
    // A-fragments of Wh for this wave's 64 out cols: A[m=l16][k=quad*8+j], m = w*64+c*16+l16
    bf16x8 whf[4][8];
#pragma unroll
    for (int c = 0; c < 4; ++c) {
        const bf16_t* p = wi2h + (long)(w * 64 + c * 16 + l16) * 512 + 256 + quad * 8;
#pragma unroll
        for (int ks = 0; ks < 8; ++ks) whf[c][ks] = *(const bf16x8*)(p + ks * 32);
    }
    // h0 -> hbuf[0] (bf16, [batch][col] padded rows)
    {
        int b = tid >> 4, e0 = (tid & 15) * 16;
        const float4* src = (const float4*)(h0 + b * 256 + e0);
        bf16_t* dst = &hbuf[0][b * HS + e0];
#pragma unroll
        for (int j = 0; j < 4; ++j) {
            float4 v = src[j];
            bf16x4 o;
            o[0] = (bf16_t)v.x; o[1] = (bf16_t)v.y; o[2] = (bf16_t)v.z; o[3] = (bf16_t)v.w;
            *(bf16x4*)(dst + j * 4) = o;
        }
    }
    // x ring: fill slots for t=0..3
    const bf16_t* xbase = xpb + (long)tid * 16;
    bf16x8 xr[4][2];
#pragma unroll
    for (int j = 0; j < 4; ++j) {
        const bf16_t* p = xbase + (long)j * 4096;
        xr[j][0] = *(const bf16x8*)p;
        xr[j][1] = *(const bf16x8*)(p + 8);
    }
    __syncthreads();
    f32x4 zero = {0.f, 0.f, 0.f, 0.f};
    for (int tb = 0; tb < 1024; tb += 4) {
#pragma unroll
        for (int j = 0; j < 4; ++j) {
            int t = tb + j;
            const bf16_t* hb = hbuf[t & 1];
            bf16_t* hn = hbuf[(t + 1) & 1];
            f32x4 accL[4], accH[4];
#pragma unroll
            for (int c = 0; c < 4; ++c) {
                f32x4 xi;
#pragma unroll
                for (int r = 0; r < 4; ++r) xi[r] = (float)xr[j][c >> 1][(c & 1) * 4 + r];
                accL[c] = xi;
                accH[c] = zero;
            }
            // prefetch t+4 into the just-consumed slot (wraps to valid addr at tail)
            {
                const bf16_t* p = xbase + (long)((t + 4) & 1023) * 4096;
                xr[j][0] = *(const bf16x8*)p;
                xr[j][1] = *(const bf16x8*)(p + 8);
            }
            bf16x8 hfrag[4];
#pragma unroll
            for (int ks = 0; ks < 4; ++ks)
                hfrag[ks] = *(const bf16x8*)(hb + l16 * HS + ks * 32 + quad * 8);
#pragma unroll
            for (int ks = 0; ks < 4; ++ks)
#pragma unroll
                for (int c = 0; c < 4; ++c) accL[c] = mfma16(whf[c][ks], hfrag[ks], accL[c]);
#pragma unroll
            for (int ks = 0; ks < 4; ++ks)
                hfrag[ks] = *(const bf16x8*)(hb + l16 * HS + (ks + 4) * 32 + quad * 8);
#pragma unroll
            for (int ks = 0; ks < 4; ++ks)
#pragma unroll
                for (int c = 0; c < 4; ++c) accH[c] = mfma16(whf[c][ks + 4], hfrag[ks], accH[c]);
#pragma unroll
            for (int c = 0; c < 4; ++c) {
                f32x4 u4 = accL[c] + accH[c];
                bf16x4 o;
#pragma unroll
                for (int r = 0; r < 4; ++r) {
                    float ex = fminf(__expf(-2.f * u4[r]), 1e37f);
                    float th = (1.f - ex) * __builtin_amdgcn_rcpf(1.f + ex);
                    o[r] = (bf16_t)fmaxf(th, 0.f);  // relu(tanh(u)) == tanh(u)*(u>0)
                }
                *(bf16x4*)(hn + l16 * HS + w * 64 + c * 16 + quad * 4) = o;
            }
            BARRIER_LGKM();
        }
    }
    // ssm = h_final @ h2o^T + b (h_final in hbuf[0] since 1024 is even)
    const bf16_t* hf = hbuf[0];
    float* ssm_out = d_out + 32 + 4194304;
#pragma unroll
    for (int c = 0; c < 4; ++c) {
        const bf16_t* p = wh2o + (long)(w * 64 + c * 16 + l16) * 256 + quad * 8;
        f32x4 a = zero;
#pragma unroll
        for (int ks = 0; ks < 8; ++ks) {
            bf16x8 af = *(const bf16x8*)(hf + l16 * HS + ks * 32 + quad * 8);
            a = mfma16(*(const bf16x8*)(p + ks * 32), af, a);
        }
        float4 bv = *(const float4*)(h2o_b + w * 64 + c * 16 + quad * 4);
        float4 v = {a[0] + bv.x, a[1] + bv.y, a[2] + bv.z, a[3] + bv.w};
        *(float4*)(ssm_out + (long)l16 * 256 + w * 64 + c * 16 + quad * 4) = v;
        *(float4*)(&ssm_lds[l16 * 256 + w * 64 + c * 16 + quad * 4]) = v;
    }
    __syncthreads();
    // logits + sigmoid: 16 threads/batch, shfl-reduce
    {
        int b = tid >> 4, sub = tid & 15;
        float s = 0.f;
#pragma unroll
        for (int j = 0; j < 16; ++j) s += ssm_lds[b * 256 + sub * 16 + j] * cls_W[sub * 16 + j];
        s += __shfl_xor(s, 1);
        s += __shfl_xor(s, 2);
        s += __shfl_xor(s, 4);
        s += __shfl_xor(s, 8);
        if (sub == 0) {
            float lg = s + cls_b[0];
            d_out[b] = lg;
            d_out[16 + b] = 1.f / (1.f + __expf(-lg));
        }
    }
}

extern "C" void kernel_launch(void* const* d_in, const int* in_sizes, int n_in,
                              void* d_out, int out_size, void* d_ws, size_t ws_size,
                              hipStream_t stream) {
    const float* text_emb = (const float*)d_in[0];
    const float* pos_emb  = (const float*)d_in[4];
    const float* text_W   = (const float*)d_in[5];
    const float* text_b   = (const float*)d_in[6];
    const float* ln1_g    = (const float*)d_in[9];
    const float* ln1_b    = (const float*)d_in[10];
    const float* qkv_W    = (const float*)d_in[11];
    const float* qkv_b    = (const float*)d_in[12];
    const float* out_W    = (const float*)d_in[13];
    const float* out_b    = (const float*)d_in[14];
    const float* ln2_g    = (const float*)d_in[15];
    const float* ln2_b    = (const float*)d_in[16];
    const float* ffn_W1   = (const float*)d_in[17];
    const float* ffn_b1   = (const float*)d_in[18];
    const float* ffn_W2   = (const float*)d_in[19];
    const float* ffn_b2   = (const float*)d_in[20];
    const float* cls_W    = (const float*)d_in[21];
    const float* cls_b    = (const float*)d_in[22];
    const float* i2h_W    = (const float*)d_in[23];
    const float* i2h_b    = (const float*)d_in[24];
    const float* h2o_W    = (const float*)d_in[25];
    const float* h2o_b    = (const float*)d_in[26];
    const float* h0       = (const float*)d_in[27];

    char* ws = (char*)d_ws;
    bf16_t* wtext = (bf16_t*)(ws + 0);         // 196608 elems
    bf16_t* wqkv  = (bf16_t*)(ws + 393216);    // 2x196608
    bf16_t* wout  = (bf16_t*)(ws + 1179648);   // 2x65536
    bf16_t* wff1  = (bf16_t*)(ws + 1441792);   // 2x262144
    bf16_t* wff2  = (bf16_t*)(ws + 2490368);   // 2x262144
    bf16_t* wi2h  = (bf16_t*)(ws + 3538944);   // 131072
    bf16_t* wh2o  = (bf16_t*)(ws + 3801088);   // 65536
    bf16_t* buf1  = (bf16_t*)(ws + 4194304);   // 33.5 MB: text_bf16 / ffn_hidden
    bf16_t* buf2  = (bf16_t*)(ws + 37748736);  // 25.2 MB: qkv bf16 (later xpb bf16)
    bf16_t* buf3  = (bf16_t*)(ws + 62914560);  // 8.4 MB: ln_out / x_bf16
    bf16_t* buf4  = (bf16_t*)(ws + 71303168);  // 8.4 MB: ctx bf16
    bf16_t* buf5  = (bf16_t*)(ws + 79691776);  // 8.4 MB: Vt bf16
    bf16_t* xpb   = (bf16_t*)(ws + 37748736);  // alias buf2 (qkv dead by then): [1024][256][16]
    float*  xbuf  = (float*)d_out + 32;        // residual stream lives in final_vector slot

    auto cast = [&](const float* s, bf16_t* d, long n) {
        cast4_k<<<(int)((n / 4 + 255) / 256), 256, 0, stream>>>(s, d, (int)(n / 4));
    };
    cast(text_W, wtext, 196608);
    cast(qkv_W, wqkv, 393216);
    cast(out_W, wout, 131072);
    cast(ffn_W1, wff1, 524288);
    cast(ffn_W2, wff2, 524288);
    cast(i2h_W, wi2h, 131072);
    cast(h2o_W, wh2o, 65536);
    cast(text_emb, buf1, (long)16384 * 768);

    // x = text_bf16 @ text_W^T + b + pos
    gemm_bt<EPI_PROJ><<<256 * 4, 256, 0, stream>>>(buf1, 768, wtext, 768, text_b, 256, 768,
                                                   nullptr, 0, xbuf, pos_emb, nullptr);
    for (int l = 0; l < 2; ++l) {
        ln_k<<<4096, 256, 0, stream>>>(xbuf, ln1_g + l * 256, ln1_b + l * 256, buf3);
        gemm_bt<EPI_QKV><<<256 * 12, 256, 0, stream>>>(buf3, 256, wqkv + l * 196608, 256,
                                                       qkv_b + l * 768, 768, 256,
                                                       buf2, 768, nullptr, nullptr, buf5);
        attn_k<<<2048, 256, 0, stream>>>(buf2, buf5, buf4);
        gemm_bt<EPI_RESID><<<256 * 4, 256, 0, stream>>>(buf4, 256, wout + l * 65536, 256,
                                                        out_b + l * 256, 256, 256,
                                                        nullptr, 0, xbuf, nullptr, nullptr);
        ln_k<<<4096, 256, 0, stream>>>(xbuf, ln2_g + l * 256, ln2_b + l * 256, buf3);
        gemm_bt<EPI_GELU><<<256 * 16, 256, 0, stream>>>(buf3, 256, wff1 + l * 262144, 256,
                                                        ffn_b1 + l * 1024, 1024, 256,
                                                        buf1, 1024, nullptr, nullptr, nullptr);
        gemm_bt<EPI_RESID><<<256 * 4, 256, 0, stream>>>(buf1, 1024, wff2 + l * 262144, 1024,
                                                        ffn_b2 + l * 256, 256, 1024,
                                                        nullptr, 0, xbuf, nullptr, nullptr);
    }
    // RNN head
    cast(xbuf, buf3, (long)16384 * 256);
    gemm_bt<EPI_XPROJ><<<256 * 4, 256, 0, stream>>>(buf3, 256, wi2h, 512, i2h_b, 256, 256,
                                                    xpb, 0, nullptr, nullptr, nullptr);
    scan_k<<<1, 256, 0, stream>>>(xpb, wi2h, wh2o, h2o_b, cls_W, cls_b, h0, (float*)d_out);
}

// Round 5
// 1776.438 us; speedup vs baseline: 1.4496x; 1.1573x over previous
//
#include <hip/hip_runtime.h>
#include <hip/hip_bf16.h>
#include <math.h>

typedef __bf16 bf16_t;
typedef __bf16 bf16x8 __attribute__((ext_vector_type(8)));
typedef __bf16 bf16x4 __attribute__((ext_vector_type(4)));
typedef float  f32x4  __attribute__((ext_vector_type(4)));

#define DEVI static __device__ __forceinline__

// workgroup barrier WITHOUT the vmcnt(0) drain __syncthreads() emits:
// LDS ordering only (lgkmcnt). Global prefetch loads stay in flight across it;
// the compiler still inserts vmcnt(N) at the register USE of loaded values.
#define BARRIER_LGKM() __asm volatile("s_waitcnt lgkmcnt(0)\n\ts_barrier" ::: "memory")

DEVI f32x4 mfma16(bf16x8 a, bf16x8 b, f32x4 c) {
    return __builtin_amdgcn_mfma_f32_16x16x32_bf16(a, b, c, 0, 0, 0);
}

// ---------------- fp32 -> bf16 cast (4 elems/thread) ----------------
__global__ void cast4_k(const float* __restrict__ src, bf16_t* __restrict__ dst, int n4) {
    int i = blockIdx.x * 256 + threadIdx.x;
    if (i < n4) {
        float4 v = ((const float4*)src)[i];
        bf16x4 o;
        o[0] = (bf16_t)v.x; o[1] = (bf16_t)v.y; o[2] = (bf16_t)v.z; o[3] = (bf16_t)v.w;
        *(bf16x4*)(dst + (long)i * 4) = o;
    }
}

// ---------------- LayerNorm: fp32 in -> bf16 out, one wave per row (E=256) ----------------
__global__ __launch_bounds__(256) void ln_k(const float* __restrict__ x,
                                            const float* __restrict__ g,
                                            const float* __restrict__ bta,
                                            bf16_t* __restrict__ out) {
    int wave = threadIdx.x >> 6, lane = threadIdx.x & 63;
    int row = blockIdx.x * 4 + wave;
    const float4 v = *(const float4*)(x + (long)row * 256 + lane * 4);
    float s  = v.x + v.y + v.z + v.w;
    float s2 = v.x * v.x + v.y * v.y + v.z * v.z + v.w * v.w;
    for (int m = 1; m < 64; m <<= 1) { s += __shfl_xor(s, m); s2 += __shfl_xor(s2, m); }
    float mu  = s * (1.f / 256.f);
    float var = s2 * (1.f / 256.f) - mu * mu;
    float rs  = rsqrtf(var + 1e-5f);
    float4 gg = *(const float4*)(g + lane * 4);
    float4 bb = *(const float4*)(bta + lane * 4);
    bf16x4 o;
    o[0] = (bf16_t)((v.x - mu) * rs * gg.x + bb.x);
    o[1] = (bf16_t)((v.y - mu) * rs * gg.y + bb.y);
    o[2] = (bf16_t)((v.z - mu) * rs * gg.z + bb.z);
    o[3] = (bf16_t)((v.w - mu) * rs * gg.w + bb.w);
    *(bf16x4*)(out + (long)row * 256 + lane * 4) = o;
}

// ---------------- generic bf16 MFMA GEMM: C[M,N] = A[M,K] @ W[N,K]^T + bias ----------------
enum { EPI_PROJ = 0, EPI_QKV = 1, EPI_RESID = 2, EPI_GELU = 3, EPI_XPROJ = 4 };

template <int EPI>
__global__ __launch_bounds__(256) void gemm_bt(
    const bf16_t* __restrict__ A, int lda,
    const bf16_t* __restrict__ W, int ldw,
    const float* __restrict__ bias,
    int N, int K,
    bf16_t* __restrict__ outb, int ldob,
    float* __restrict__ outf,
    const float* __restrict__ pos,
    bf16_t* __restrict__ vt) {
    int tiles_n = N >> 6;
    int tm = blockIdx.x / tiles_n, tn = blockIdx.x % tiles_n;
    int wave = threadIdx.x >> 6, lane = threadIdx.x & 63;
    int quad = lane >> 4, l16 = lane & 15;
    int m0 = tm * 64 + wave * 16;
    int n0 = tn * 64;
    const bf16_t* a_ptr = A + (long)(m0 + l16) * lda + quad * 8;
    const bf16_t* w_ptr = W + (long)(n0 + l16) * ldw + quad * 8;
    f32x4 zero = {0.f, 0.f, 0.f, 0.f};
    f32x4 acc[4] = {zero, zero, zero, zero};
    for (int k = 0; k < K; k += 32) {
        bf16x8 af = *(const bf16x8*)(a_ptr + k);
#pragma unroll
        for (int c = 0; c < 4; ++c) {
            bf16x8 wf = *(const bf16x8*)(w_ptr + (long)c * 16 * ldw + k);
            acc[c] = mfma16(af, wf, acc[c]);
        }
    }
#pragma unroll
    for (int c = 0; c < 4; ++c) {
        int col = n0 + c * 16 + l16;
        float bv = bias[col];
#pragma unroll
        for (int r = 0; r < 4; ++r) {
            int row = m0 + quad * 4 + r;
            float v = acc[c][r] + bv;
            if (EPI == EPI_PROJ) {
                int s = row & 1023;
                v += pos[(long)s * 256 + col];
                outf[(long)row * 256 + col] = v;
            } else if (EPI == EPI_QKV) {
                outb[(long)row * ldob + col] = (bf16_t)v;
                if (col >= 512) {  // emit V transposed: Vt[b*8+h][d][s]
                    int b = row >> 10, s = row & 1023;
                    int hh = (col - 512) >> 5, d = (col - 512) & 31;
                    vt[(((long)(b * 8 + hh) * 32 + d) << 10) + s] = (bf16_t)v;
                }
            } else if (EPI == EPI_RESID) {
                float* p = outf + (long)row * 256 + col;
                *p = *p + v;
            } else if (EPI == EPI_GELU) {
                float gg = 0.5f * v * (1.f + erff(v * 0.70710678118654752f));
                outb[(long)row * ldob + col] = (bf16_t)gg;
            } else if (EPI == EPI_XPROJ) {
                // xp fp32 [s][b][256], cols permuted so scan consumer thread tid
                // (col = w*64 + (l16>>2)*16 + quad*4 + (l16&3)) reads index tid.
                int b = row >> 10, s = row & 1023;
                int tcons = (col & ~63) | (((col >> 2) & 3) << 4) | (((col >> 4) & 3) << 2) | (col & 3);
                outf[((long)s * 16 + b) * 256 + tcons] = v;
            }
        }
    }
}

// ---------------- flash attention: one wave = 16 q rows, online softmax ----------------
__global__ __launch_bounds__(256) void attn_k(const bf16_t* __restrict__ qkv,  // [16384,768]
                                              const bf16_t* __restrict__ vt,   // [128][32][1024]
                                              bf16_t* __restrict__ ctx) {      // [16384,256]
    __shared__ bf16_t Pbuf[4][16 * 32];
    int wave = threadIdx.x >> 6, lane = threadIdx.x & 63;
    int quad = lane >> 4, l16 = lane & 15;
    int bh = blockIdx.x >> 4;
    int b = bh >> 3, h = bh & 7;
    int q0 = ((blockIdx.x & 15) * 4 + wave) * 16;
    const bf16_t* qbase = qkv + (long)(b * 1024 + q0 + l16) * 768 + h * 32 + quad * 8;
    bf16x8 qf = *(const bf16x8*)qbase;  // DH=32 == MFMA K: load Q fragment once
    const bf16_t* kbase = qkv + (long)(b * 1024 + l16) * 768 + 256 + h * 32 + quad * 8;
    const bf16_t* vbase = vt + ((long)bh * 32) * 1024;
    f32x4 zero = {0.f, 0.f, 0.f, 0.f};
    f32x4 ca = zero, cb = zero;
    float mrow[4] = {-INFINITY, -INFINITY, -INFINITY, -INFINITY};
    float lrow[4] = {0.f, 0.f, 0.f, 0.f};
    bf16_t* P = Pbuf[wave];
    const float sc = 0.17677669529663687f;  // 1/sqrt(32)
    for (int kb = 0; kb < 1024; kb += 32) {
        bf16x8 kf0 = *(const bf16x8*)(kbase + (long)kb * 768);
        bf16x8 kf1 = *(const bf16x8*)(kbase + (long)(kb + 16) * 768);
        f32x4 s0 = mfma16(qf, kf0, zero);
        f32x4 s1 = mfma16(qf, kf1, zero);
        float p0[4], p1[4];
#pragma unroll
        for (int r = 0; r < 4; ++r) {
            float a0 = s0[r] * sc, a1 = s1[r] * sc;
            float mx = fmaxf(a0, a1);
            mx = fmaxf(mx, __shfl_xor(mx, 1));
            mx = fmaxf(mx, __shfl_xor(mx, 2));
            mx = fmaxf(mx, __shfl_xor(mx, 4));
            mx = fmaxf(mx, __shfl_xor(mx, 8));
            float mn = fmaxf(mrow[r], mx);
            float alpha = __expf(mrow[r] - mn);
            mrow[r] = mn;
            float e0 = __expf(a0 - mn), e1 = __expf(a1 - mn);
            float rs = e0 + e1;
            rs += __shfl_xor(rs, 1);
            rs += __shfl_xor(rs, 2);
            rs += __shfl_xor(rs, 4);
            rs += __shfl_xor(rs, 8);
            lrow[r] = lrow[r] * alpha + rs;
            ca[r] *= alpha;
            cb[r] *= alpha;
            p0[r] = e0; p1[r] = e1;
        }
#pragma unroll
        for (int r = 0; r < 4; ++r) {
            P[(quad * 4 + r) * 32 + l16] = (bf16_t)p0[r];
            P[(quad * 4 + r) * 32 + 16 + l16] = (bf16_t)p1[r];
        }
        BARRIER_LGKM();
        bf16x8 pf = *(const bf16x8*)(P + l16 * 32 + quad * 8);  // A-layout read-back
        bf16x8 vf0 = *(const bf16x8*)(vbase + (long)l16 * 1024 + kb + quad * 8);
        bf16x8 vf1 = *(const bf16x8*)(vbase + (long)(16 + l16) * 1024 + kb + quad * 8);
        ca = mfma16(pf, vf0, ca);
        cb = mfma16(pf, vf1, cb);
        BARRIER_LGKM();
    }
#pragma unroll
    for (int r = 0; r < 4; ++r) {
        float inv = 1.f / lrow[r];
        long row = (long)(b * 1024 + q0 + quad * 4 + r);
        ctx[row * 256 + h * 32 + l16] = (bf16_t)(ca[r] * inv);
        ctx[row * 256 + h * 32 + 16 + l16] = (bf16_t)(cb[r] * inv);
    }
}

// ---------------- RNN scan v5: batch-parallel, 16 workgroups (1 batch = 1 CU) ----------------
// Matvec u = Wh·h via MFMA with h BROADCAST into all 16 B-operand N-slots (same-address
// LDS reads broadcast free). D is replicated across n=l16, so each lane selects its own
// output column from registers via a loop-invariant cndmask tree -> 1 tanh/thread,
// 1 barrier/step, no u round-trip. x fp32, pre-permuted so thread tid loads index tid.
__global__ __launch_bounds__(256, 1) void scan_k(const float* __restrict__ xp,    // [1024][16][256] permuted
                                                 const bf16_t* __restrict__ wi2h, // [256][512]
                                                 const bf16_t* __restrict__ wh2o, // [256][256]
                                                 const float* __restrict__ h2o_b,
                                                 const float* __restrict__ cls_W,
                                                 const float* __restrict__ cls_b,
                                                 const float* __restrict__ h0,
                                                 float* __restrict__ d_out) {
    __shared__ bf16_t hbuf[2][256];
    __shared__ float red[4];
    int tid = threadIdx.x, b = blockIdx.x;
    int w = tid >> 6, lane = tid & 63, quad = lane >> 4, l16 = lane & 15;
    // A-fragments of Wh (rows = this wave's 64 out cols), register-resident
    bf16x8 whf[4][8];
#pragma unroll
    for (int c = 0; c < 4; ++c) {
        const bf16_t* p = wi2h + (long)(w * 64 + c * 16 + l16) * 512 + 256 + quad * 8;
#pragma unroll
        for (int ks = 0; ks < 8; ++ks) whf[c][ks] = *(const bf16x8*)(p + ks * 32);
    }
    // this thread's output column after the cndmask redistribution
    int mycol = w * 64 + ((l16 >> 2) << 4) + (quad << 2) + (l16 & 3);
    hbuf[0][tid] = (bf16_t)h0[b * 256 + tid];
    // x ring, depth 4 (stays in flight across lgkm-only barrier)
    float xr[4];
#pragma unroll
    for (int j = 0; j < 4; ++j) xr[j] = xp[((long)j * 16 + b) * 256 + tid];
    const bool c0s = (l16 >> 2) & 1, c1s = (l16 >> 3) & 1, r0s = l16 & 1, r1s = (l16 >> 1) & 1;
    __syncthreads();
    f32x4 zero = {0.f, 0.f, 0.f, 0.f};
    for (int t = 0; t < 1024; ++t) {
        const bf16_t* hb = hbuf[t & 1];
        bf16x8 hfrag[8];
#pragma unroll
        for (int ks = 0; ks < 8; ++ks) hfrag[ks] = *(const bf16x8*)(hb + ks * 32 + quad * 8);
        f32x4 acc[4];
#pragma unroll
        for (int c = 0; c < 4; ++c) acc[c] = mfma16(whf[c][0], hfrag[0], zero);
#pragma unroll
        for (int ks = 1; ks < 8; ++ks)
#pragma unroll
            for (int c = 0; c < 4; ++c) acc[c] = mfma16(whf[c][ks], hfrag[ks], acc[c]);
        // select u = acc[c = l16>>2][r = l16&3] (replicated across n)
        f32x4 tr;
#pragma unroll
        for (int r = 0; r < 4; ++r) {
            float a01 = c0s ? acc[1][r] : acc[0][r];
            float a23 = c0s ? acc[3][r] : acc[2][r];
            tr[r] = c1s ? a23 : a01;
        }
        float s0v = r0s ? tr[1] : tr[0];
        float s1v = r0s ? tr[3] : tr[2];
        float u = (r1s ? s1v : s0v) + xr[t & 3];
        xr[t & 3] = xp[((long)((t + 4) & 1023) * 16 + b) * 256 + tid];  // prefetch t+4
        float ex = fminf(__expf(-2.f * u), 1e37f);
        float th = (1.f - ex) * __builtin_amdgcn_rcpf(1.f + ex);
        hbuf[(t + 1) & 1][mycol] = (bf16_t)fmaxf(th, 0.f);  // relu(tanh(u)) == tanh(u)*(u>0)
        BARRIER_LGKM();
    }
    // ssm = h_final @ h2o^T + bias (same broadcast structure; h_final in hbuf[0])
    {
        const bf16_t* hf = hbuf[0];
        bf16x8 hfrag[8];
#pragma unroll
        for (int ks = 0; ks < 8; ++ks) hfrag[ks] = *(const bf16x8*)(hf + ks * 32 + quad * 8);
        f32x4 acc[4];
#pragma unroll
        for (int c = 0; c < 4; ++c) {
            const bf16_t* p = wh2o + (long)(w * 64 + c * 16 + l16) * 256 + quad * 8;
            acc[c] = mfma16(*(const bf16x8*)p, hfrag[0], zero);
#pragma unroll
            for (int ks = 1; ks < 8; ++ks)
                acc[c] = mfma16(*(const bf16x8*)(p + ks * 32), hfrag[ks], acc[c]);
        }
        f32x4 tr;
#pragma unroll
        for (int r = 0; r < 4; ++r) {
            float a01 = c0s ? acc[1][r] : acc[0][r];
            float a23 = c0s ? acc[3][r] : acc[2][r];
            tr[r] = c1s ? a23 : a01;
        }
        float s0v = r0s ? tr[1] : tr[0];
        float s1v = r0s ? tr[3] : tr[2];
        float v = (r1s ? s1v : s0v) + h2o_b[mycol];
        d_out[32 + 4194304 + (long)b * 256 + mycol] = v;
        // logits + sigmoid
        float part = v * cls_W[mycol];
#pragma unroll
        for (int m = 1; m < 64; m <<= 1) part += __shfl_xor(part, m);
        if (lane == 0) red[w] = part;
        __syncthreads();
        if (tid == 0) {
            float lg = red[0] + red[1] + red[2] + red[3] + cls_b[0];
            d_out[b] = lg;
            d_out[16 + b] = 1.f / (1.f + __expf(-lg));
        }
    }
}

extern "C" void kernel_launch(void* const* d_in, const int* in_sizes, int n_in,
                              void* d_out, int out_size, void* d_ws, size_t ws_size,
                              hipStream_t stream) {
    const float* text_emb = (const float*)d_in[0];
    const float* pos_emb  = (const float*)d_in[4];
    const float* text_W   = (const float*)d_in[5];
    const float* text_b   = (const float*)d_in[6];
    const float* ln1_g    = (const float*)d_in[9];
    const float* ln1_b    = (const float*)d_in[10];
    const float* qkv_W    = (const float*)d_in[11];
    const float* qkv_b    = (const float*)d_in[12];
    const float* out_W    = (const float*)d_in[13];
    const float* out_b    = (const float*)d_in[14];
    const float* ln2_g    = (const float*)d_in[15];
    const float* ln2_b    = (const float*)d_in[16];
    const float* ffn_W1   = (const float*)d_in[17];
    const float* ffn_b1   = (const float*)d_in[18];
    const float* ffn_W2   = (const float*)d_in[19];
    const float* ffn_b2   = (const float*)d_in[20];
    const float* cls_W    = (const float*)d_in[21];
    const float* cls_b    = (const float*)d_in[22];
    const float* i2h_W    = (const float*)d_in[23];
    const float* i2h_b    = (const float*)d_in[24];
    const float* h2o_W    = (const float*)d_in[25];
    const float* h2o_b    = (const float*)d_in[26];
    const float* h0       = (const float*)d_in[27];

    char* ws = (char*)d_ws;
    bf16_t* wtext = (bf16_t*)(ws + 0);         // 196608 elems
    bf16_t* wqkv  = (bf16_t*)(ws + 393216);    // 2x196608
    bf16_t* wout  = (bf16_t*)(ws + 1179648);   // 2x65536
    bf16_t* wff1  = (bf16_t*)(ws + 1441792);   // 2x262144
    bf16_t* wff2  = (bf16_t*)(ws + 2490368);   // 2x262144
    bf16_t* wi2h  = (bf16_t*)(ws + 3538944);   // 131072
    bf16_t* wh2o  = (bf16_t*)(ws + 3801088);   // 65536
    bf16_t* buf1  = (bf16_t*)(ws + 4194304);   // 33.5 MB: text_bf16 / ffn_hidden
    bf16_t* buf2  = (bf16_t*)(ws + 37748736);  // 25.2 MB: qkv bf16 (later xp fp32)
    bf16_t* buf3  = (bf16_t*)(ws + 62914560);  // 8.4 MB: ln_out / x_bf16
    bf16_t* buf4  = (bf16_t*)(ws + 71303168);  // 8.4 MB: ctx bf16
    bf16_t* buf5  = (bf16_t*)(ws + 79691776);  // 8.4 MB: Vt bf16
    float*  xp    = (float*)(ws + 37748736);   // alias buf2 (qkv dead by then): fp32 [1024][16][256]
    float*  xbuf  = (float*)d_out + 32;        // residual stream lives in final_vector slot

    auto cast = [&](const float* s, bf16_t* d, long n) {
        cast4_k<<<(int)((n / 4 + 255) / 256), 256, 0, stream>>>(s, d, (int)(n / 4));
    };
    cast(text_W, wtext, 196608);
    cast(qkv_W, wqkv, 393216);
    cast(out_W, wout, 131072);
    cast(ffn_W1, wff1, 524288);
    cast(ffn_W2, wff2, 524288);
    cast(i2h_W, wi2h, 131072);
    cast(h2o_W, wh2o, 65536);
    cast(text_emb, buf1, (long)16384 * 768);

    // x = text_bf16 @ text_W^T + b + pos
    gemm_bt<EPI_PROJ><<<256 * 4, 256, 0, stream>>>(buf1, 768, wtext, 768, text_b, 256, 768,
                                                   nullptr, 0, xbuf, pos_emb, nullptr);
    for (int l = 0; l < 2; ++l) {
        ln_k<<<4096, 256, 0, stream>>>(xbuf, ln1_g + l * 256, ln1_b + l * 256, buf3);
        gemm_bt<EPI_QKV><<<256 * 12, 256, 0, stream>>>(buf3, 256, wqkv + l * 196608, 256,
                                                       qkv_b + l * 768, 768, 256,
                                                       buf2, 768, nullptr, nullptr, buf5);
        attn_k<<<2048, 256, 0, stream>>>(buf2, buf5, buf4);
        gemm_bt<EPI_RESID><<<256 * 4, 256, 0, stream>>>(buf4, 256, wout + l * 65536, 256,
                                                        out_b + l * 256, 256, 256,
                                                        nullptr, 0, xbuf, nullptr, nullptr);
        ln_k<<<4096, 256, 0, stream>>>(xbuf, ln2_g + l * 256, ln2_b + l * 256, buf3);
        gemm_bt<EPI_GELU><<<256 * 16, 256, 0, stream>>>(buf3, 256, wff1 + l * 262144, 256,
                                                        ffn_b1 + l * 1024, 1024, 256,
                                                        buf1, 1024, nullptr, nullptr, nullptr);
        gemm_bt<EPI_RESID><<<256 * 4, 256, 0, stream>>>(buf1, 1024, wff2 + l * 262144, 1024,
                                                        ffn_b2 + l * 256, 256, 1024,
                                                        nullptr, 0, xbuf, nullptr, nullptr);
    }
    // RNN head
    cast(xbuf, buf3, (long)16384 * 256);
    gemm_bt<EPI_XPROJ><<<256 * 4, 256, 0, stream>>>(buf3, 256, wi2h, 512, i2h_b, 256, 256,
                                                    nullptr, 0, xp, nullptr, nullptr);
    scan_k<<<16, 256, 0, stream>>>(xp, wi2h, wh2o, h2o_b, cls_W, cls_b, h0, (float*)d_out);
}